// Round 4
// baseline (9690.778 us; speedup 1.0000x reference)
//
#include <hip/hip_runtime.h>
#include <math.h>

#define DIM      1024
#define K_GATES  24
#define NMAX     512          // max Chebyshev terms per gate
#define QUAD_M   2048         // quadrature points for Bessel J_n
#define BBOUND   66.0f        // spectral bound: GUE radius 64 + 3% margin
#define ROWS     16           // rows per block
#define NBLOCKS  64           // 64 * 16 = 1024 rows
#define NTHREADS 1024         // 16 waves of 64
#define PSLOT    8            // vector-slot ring depth (protocol needs >= 4)
#define CANARY   0x7FBADEAD7FBADEADull   // NaN|NaN payload: never a legit amplitude

union F2U { unsigned long long u; float2 f; };

// relaxed agent-scope (MALL-coherent) 8-byte ops — proven in R0/R2
__device__ __forceinline__ unsigned long long ld64coh(const unsigned long long* p) {
    return __hip_atomic_load(p, __ATOMIC_RELAXED, __HIP_MEMORY_SCOPE_AGENT);
}
__device__ __forceinline__ void st64coh(unsigned long long* p, unsigned long long v) {
    __hip_atomic_store(p, v, __ATOMIC_RELAXED, __HIP_MEMORY_SCOPE_AGENT);
}

// ---------------------------------------------------------------- init state
// slot0 = pad(feature,1024)/||feature||; slots 1..PSLOT-1 = CANARY; bars = 0
__global__ __launch_bounds__(1024) void init_state(const float* __restrict__ f,
                                                   int nfeat,
                                                   unsigned long long* __restrict__ slots,
                                                   unsigned int* __restrict__ bars) {
    __shared__ float red[16];
    __shared__ float invn_s;
    int t = threadIdx.x;
    float v = (t < nfeat) ? f[t] : 0.f;
    float s = v * v;
    #pragma unroll
    for (int o = 1; o < 64; o <<= 1) s += __shfl_xor(s, o);
    if ((t & 63) == 0) red[t >> 6] = s;
    __syncthreads();
    if (t == 0) {
        float tot = 0.f;
        for (int i = 0; i < 16; i++) tot += red[i];
        invn_s = 1.0f / sqrtf(tot);
    }
    __syncthreads();
    F2U c; c.f = make_float2(v * invn_s, 0.f);
    slots[t] = c.u;
    #pragma unroll
    for (int p = 1; p < PSLOT; p++) slots[(size_t)p * DIM + t] = CANARY;
    if (t < 160) bars[t] = 0u;      // 8 group ctrs (stride 16 u32) + root
}

// ---------------------------------------------------------------- Bessel coefs
// c_n(k) = (n==0?1:2) * (-i)^n * J_n(tau_k),  tau_k = theta_k * BBOUND
__global__ __launch_bounds__(256) void bessel_coef(const float* __restrict__ theta,
                                                   float2* __restrict__ coefs) {
    int n = blockIdx.x;   // 0..NMAX-1
    int k = blockIdx.y;   // 0..K_GATES-1
    double tau = (double)theta[k] * (double)BBOUND;
    int t = threadIdx.x;  // 256
    double acc = 0.0;
    #pragma unroll
    for (int i = 0; i < QUAD_M / 256; i++) {
        int j = t + 256 * i;
        double phi = (2.0 * M_PI / (double)QUAD_M) * (double)j;
        acc += cos((double)n * phi - tau * sin(phi));
    }
    #pragma unroll
    for (int o = 1; o < 64; o <<= 1) acc += __shfl_xor(acc, o);
    __shared__ double red[4];
    if ((t & 63) == 0) red[t >> 6] = acc;
    __syncthreads();
    if (t == 0) {
        double J = (red[0] + red[1] + red[2] + red[3]) / (double)QUAD_M;
        double f = (n == 0) ? 1.0 : 2.0;
        float cr = 0.f, cim = 0.f;
        switch (n & 3) {                 // (-i)^n
            case 0: cr  =  (float)(f * J); break;
            case 1: cim = -(float)(f * J); break;
            case 2: cr  = -(float)(f * J); break;
            case 3: cim =  (float)(f * J); break;
        }
        coefs[k * NMAX + n] = make_float2(cr, cim);
    }
}

// ---------------------------------------------------------------- truncation
__global__ __launch_bounds__(NMAX) void trunc_len(const float2* __restrict__ coefs,
                                                  int* __restrict__ nterm) {
    int k = blockIdx.x;
    int t = threadIdx.x;  // 512
    float2 c = coefs[k * NMAX + t];
    float mag = fabsf(c.x) + fabsf(c.y);
    int myn = (mag > 5e-7f) ? t : 0;
    #pragma unroll
    for (int o = 1; o < 64; o <<= 1) myn = max(myn, __shfl_xor(myn, o));
    __shared__ int red[8];
    if ((t & 63) == 0) red[t >> 6] = myn;
    __syncthreads();
    if (t == 0) {
        int m = 1;
        for (int i = 0; i < 8; i++) m = max(m, red[i]);
        nterm[k] = min(m, NMAX - 1);
    }
}

// ---------------------------------------------------------------- main kernel
//
// Hybrid exchange (all primitives proven in R0/R2 on this HW):
//  * Round rho publishes into ring slot[rho%8] (CANARY-armed, R2 protocol).
//    Round rho publishes acc on its LAST gate-round (T_N itself is never
//    consumed), saving the epilogue round per gate.
//  * Sync via a 2-level arrival tree of MONOTONE agent-scope counters:
//    8 groups of 8 blocks (strided 64B lines); last-in-group bumps root.
//    root == 8*rho  <=>  all 64 blocks published round rho AND their stores
//    are drained (each block's publish is vmcnt-drained by the __syncthreads
//    preceding its arrival RMW).
//  * Load path is SPECULATIVE: right after the drain barrier each thread
//    issues its component load (concurrent with tree+detect). Lockstep from
//    the barrier makes most specs hit; stragglers re-poll with an LDS
//    go-flag escape; one post-release load is guaranteed fresh. Bounded
//    (<= ~2 loads/thread/round) — avoids R1/R2's MALL flood.
//  * Re-arm slot[rho-1] after the round-rho release: root full => all blocks
//    arrived(rho) => all staged slot[rho-1] into their LDS => slot dead.
//    Republished at rho+7 (ring gap 7 >= 4 required).
//  * Liveness: only unbounded spin is t0's root poll (R0-proven shape); the
//    component poll exits via go_tag which t0 always sets after root full.
//  * Geometry: R0's proven 64x1024, 16 rows/block, 1 row/wave; Gtilde row
//    held in VGPRs (gq[8] float4 = 32 VGPR) — dot reads only xs from LDS.
__global__ __launch_bounds__(NTHREADS) void evolve(
        const float* __restrict__ gre, const float* __restrict__ gim,
        unsigned long long* __restrict__ slots,
        const float2* __restrict__ coefs, const int* __restrict__ nterm,
        unsigned int* __restrict__ bars, float* __restrict__ out) {
    __shared__ float2 Gs[ROWS * DIM];        // 128 KiB: staging scratch for Gtilde
    __shared__ float2 xs[2][DIM];            // 16 KiB double-buffered vector
    __shared__ int go_tag;                   // round tag of last detected release
    const int t = threadIdx.x, b = blockIdx.x;
    const int wave = t >> 6, lane = t & 63;
    const int r0 = b * ROWS;
    const int r = r0 + wave;                 // this wave's row
    const float hB = 0.5f / BBOUND;
    unsigned int* grp  = bars + (b >> 3) * 16;   // group counter (own 64B line)
    unsigned int* root = bars + 8 * 16;          // root counter

    // pre-stage psi (slot0, written by init_state — cross-kernel visible)
    { F2U c; c.u = ld64coh(slots + t); xs[0][t] = c.f; }
    if (t == 0) go_tag = 0;
    float2 acc = make_float2(0.f, 0.f);
    float2 t1 = acc, t2 = acc;
    int rho = 1;
    __syncthreads();

    for (int k = 0; k < K_GATES; ++k) {
        const float* R = gre + (size_t)k * DIM * DIM;
        const float* I = gim + (size_t)k * DIM * DIM;

        // ---- stage Gtilde = ((R+R^T)/2 + i(I-I^T)/2)/B into Gs (R0 code) ----
        __syncthreads();                     // prior gate's gq pulls complete
        {   // pass A: column panel R[:, r0:r0+16], I[:, r0:r0+16]
            const float4* Rc = (const float4*)(R + (size_t)t * DIM + r0);
            const float4* Ic = (const float4*)(I + (size_t)t * DIM + r0);
            float4 ra0 = Rc[0], ra1 = Rc[1], ra2 = Rc[2], ra3 = Rc[3];
            float4 ia0 = Ic[0], ia1 = Ic[1], ia2 = Ic[2], ia3 = Ic[3];
            Gs[ 0 * DIM + t] = make_float2(hB * ra0.x, -hB * ia0.x);
            Gs[ 1 * DIM + t] = make_float2(hB * ra0.y, -hB * ia0.y);
            Gs[ 2 * DIM + t] = make_float2(hB * ra0.z, -hB * ia0.z);
            Gs[ 3 * DIM + t] = make_float2(hB * ra0.w, -hB * ia0.w);
            Gs[ 4 * DIM + t] = make_float2(hB * ra1.x, -hB * ia1.x);
            Gs[ 5 * DIM + t] = make_float2(hB * ra1.y, -hB * ia1.y);
            Gs[ 6 * DIM + t] = make_float2(hB * ra1.z, -hB * ia1.z);
            Gs[ 7 * DIM + t] = make_float2(hB * ra1.w, -hB * ia1.w);
            Gs[ 8 * DIM + t] = make_float2(hB * ra2.x, -hB * ia2.x);
            Gs[ 9 * DIM + t] = make_float2(hB * ra2.y, -hB * ia2.y);
            Gs[10 * DIM + t] = make_float2(hB * ra2.z, -hB * ia2.z);
            Gs[11 * DIM + t] = make_float2(hB * ra2.w, -hB * ia2.w);
            Gs[12 * DIM + t] = make_float2(hB * ra3.x, -hB * ia3.x);
            Gs[13 * DIM + t] = make_float2(hB * ra3.y, -hB * ia3.y);
            Gs[14 * DIM + t] = make_float2(hB * ra3.z, -hB * ia3.z);
            Gs[15 * DIM + t] = make_float2(hB * ra3.w, -hB * ia3.w);
        }
        __syncthreads();
        {   // pass B: row panel (coalesced), accumulate into Gs
            const float4* Rr = (const float4*)(R + (size_t)r * DIM);
            const float4* Ir = (const float4*)(I + (size_t)r * DIM);
            float4* G4 = (float4*)(Gs + (size_t)wave * DIM);
            #pragma unroll
            for (int m = 0; m < 4; m++) {
                int i4 = lane + 64 * m;
                float4 rv = Rr[i4], iv = Ir[i4];
                float4 g0 = G4[2 * i4], g1 = G4[2 * i4 + 1];
                g0.x += hB * rv.x; g0.y += hB * iv.x;
                g0.z += hB * rv.y; g0.w += hB * iv.y;
                g1.x += hB * rv.z; g1.y += hB * iv.z;
                g1.z += hB * rv.w; g1.w += hB * iv.w;
                G4[2 * i4] = g0; G4[2 * i4 + 1] = g1;
            }
        }
        __syncthreads();
        // pull this wave's row into registers: gq[m] = G[r][2(lane+64m) .. +1]
        float4 gq[8];
        #pragma unroll
        for (int m = 0; m < 8; ++m)
            gq[m] = *(const float4*)(Gs + (size_t)wave * DIM + 2 * (lane + 64 * m));

        const int N = nterm[k];
        const float2* C = coefs + (size_t)k * NMAX;

        for (int n = 1; n <= N; ++n, ++rho) {
            unsigned long long* dst = slots + (size_t)(rho & (PSLOT - 1)) * DIM;
            const float2* xsrc = xs[(rho - 1) & 1];

            // ---- w = Gtilde_row . x (regs x LDS), all-lane butterfly ----
            float sre = 0.f, sim = 0.f;
            const float4* x4 = (const float4*)xsrc;
            #pragma unroll
            for (int m = 0; m < 8; ++m) {
                float4 xv = x4[lane + 64 * m];
                float4 gv = gq[m];
                sre += gv.x * xv.x - gv.y * xv.y + gv.z * xv.z - gv.w * xv.w;
                sim += gv.x * xv.y + gv.y * xv.x + gv.z * xv.w + gv.w * xv.z;
            }
            #pragma unroll
            for (int o = 1; o < 64; o <<= 1) {
                sre += __shfl_xor(sre, o);
                sim += __shfl_xor(sim, o);
            }

            float2 tn;
            if (n == 1) {                    // T_0 = psi (staged), T_1 = Gt psi
                tn = make_float2(sre, sim);
                const float2 p0 = xsrc[r];
                const float2 c0 = C[0], c1 = C[1];
                acc.x = c0.x * p0.x - c0.y * p0.y + c1.x * tn.x - c1.y * tn.y;
                acc.y = c0.x * p0.y + c0.y * p0.x + c1.x * tn.y + c1.y * tn.x;
                t2 = p0;
            } else {                         // T_n = 2 Gt T_{n-1} - T_{n-2}
                tn = make_float2(2.f * sre - t2.x, 2.f * sim - t2.y);
                const float2 cn = C[n];
                acc.x += cn.x * tn.x - cn.y * tn.y;
                acc.y += cn.x * tn.y + cn.y * tn.x;
                t2 = t1;
            }
            t1 = tn;
            // last gate-round publishes the NEW psi (T_N is never consumed)
            const float2 res = (n == N) ? acc : tn;

            if (lane == 0) { F2U c; c.f = res; st64coh(dst + r, c.u); }
            __syncthreads();                 // drains every thread's publish

            // speculative component load — concurrent with tree + detect
            unsigned long long u = ld64coh(dst + t);

            if (t == 0) {                    // arrival tree + release detect
                unsigned old = __hip_atomic_fetch_add(grp, 1u, __ATOMIC_RELAXED,
                                                      __HIP_MEMORY_SCOPE_AGENT);
                if ((old & 7u) == 7u)
                    __hip_atomic_fetch_add(root, 1u, __ATOMIC_RELAXED,
                                           __HIP_MEMORY_SCOPE_AGENT);
                while (__hip_atomic_load(root, __ATOMIC_RELAXED,
                                         __HIP_MEMORY_SCOPE_AGENT) < 8u * (unsigned)rho)
                    __builtin_amdgcn_s_sleep(1);
                *(volatile int*)&go_tag = rho;
            }
            // bounded poll: escape when release detected; final load then
            // guaranteed fresh (root full => all publishes at coherence point)
            while (u == CANARY && *(volatile int*)&go_tag != rho)
                u = ld64coh(dst + t);
            while (u == CANARY) u = ld64coh(dst + t);

            { F2U c; c.u = u; xs[rho & 1][t] = c.f; }
            __syncthreads();                 // xs complete; release known block-wide

            // re-arm slot[rho-1] (dead: all blocks staged it before arriving(rho))
            if (t < ROWS)
                st64coh(slots + (size_t)((rho - 1) & (PSLOT - 1)) * DIM + r0 + t,
                        CANARY);
        }
    }

    // probs = |psi|^2 (acc holds this wave's row of the final state)
    if (lane == 0) out[r] = acc.x * acc.x + acc.y * acc.y;
}

// ---------------------------------------------------------------- launch
extern "C" void kernel_launch(void* const* d_in, const int* in_sizes, int n_in,
                              void* d_out, int out_size, void* d_ws, size_t ws_size,
                              hipStream_t stream) {
    const float* feat  = (const float*)d_in[0];   // 1000
    const float* theta = (const float*)d_in[1];   // 24
    const float* gre   = (const float*)d_in[2];   // 24*1024*1024
    const float* gim   = (const float*)d_in[3];

    // ws: slots[8][1024] u64 | coefs[24][512] f2 | nterm[24] i32 | pad | bars[160] u32
    char* base = (char*)d_ws;
    unsigned long long* slots = (unsigned long long*)base;
    size_t off = (size_t)PSLOT * DIM * sizeof(unsigned long long);
    float2* coefs = (float2*)(base + off);
    off += (size_t)K_GATES * NMAX * sizeof(float2);
    int* nterm = (int*)(base + off);
    off += (size_t)K_GATES * sizeof(int);
    off = (off + 255) & ~(size_t)255;
    unsigned int* bars = (unsigned int*)(base + off);
    float* outp = (float*)d_out;

    init_state<<<1, 1024, 0, stream>>>(feat, in_sizes[0], slots, bars);
    bessel_coef<<<dim3(NMAX, K_GATES), 256, 0, stream>>>(theta, coefs);
    trunc_len<<<K_GATES, NMAX, 0, stream>>>(coefs, nterm);

    void* args[] = {(void*)&gre, (void*)&gim, (void*)&slots,
                    (void*)&coefs, (void*)&nterm, (void*)&bars, (void*)&outp};
    hipLaunchCooperativeKernel((void*)evolve, dim3(NBLOCKS), dim3(NTHREADS),
                               args, 0, stream);
}

// Round 6
// 7455.824 us; speedup vs baseline: 1.2998x; 1.2998x over previous
//
#include <hip/hip_runtime.h>
#include <math.h>

#define DIM      1024
#define K_GATES  24
#define NMAX     512          // max Chebyshev terms per gate
#define QUAD_M   2048         // quadrature points for Bessel J_n
#define BBOUND   66.0f        // spectral bound: GUE radius 64 + 3% margin
#define ROWS     16           // rows per block
#define NBLOCKS  64           // 64 * 16 = 1024 rows
#define NTHREADS 1024         // 16 waves of 64
#define PSLOT    8            // vector-slot ring depth (protocol needs >= 4)
#define CANARY   0x7FBADEAD7FBADEADull   // NaN|NaN payload: never a legit amplitude

union F2U { unsigned long long u; float2 f; };

// relaxed agent-scope (MALL-coherent) ops — proven in R0/R2/R4
__device__ __forceinline__ unsigned long long ld64coh(const unsigned long long* p) {
    return __hip_atomic_load(p, __ATOMIC_RELAXED, __HIP_MEMORY_SCOPE_AGENT);
}
__device__ __forceinline__ void st64coh(unsigned long long* p, unsigned long long v) {
    __hip_atomic_store(p, v, __ATOMIC_RELAXED, __HIP_MEMORY_SCOPE_AGENT);
}

// ---------------------------------------------------------------- init state
// slot0 = pad(feature,1024)/||feature||; slots 1..PSLOT-1 = CANARY; flags = 0
__global__ __launch_bounds__(1024) void init_state(const float* __restrict__ f,
                                                   int nfeat,
                                                   unsigned long long* __restrict__ slots,
                                                   unsigned int* __restrict__ arrive) {
    __shared__ float red[16];
    __shared__ float invn_s;
    int t = threadIdx.x;
    float v = (t < nfeat) ? f[t] : 0.f;
    float s = v * v;
    #pragma unroll
    for (int o = 1; o < 64; o <<= 1) s += __shfl_xor(s, o);
    if ((t & 63) == 0) red[t >> 6] = s;
    __syncthreads();
    if (t == 0) {
        float tot = 0.f;
        for (int i = 0; i < 16; i++) tot += red[i];
        invn_s = 1.0f / sqrtf(tot);
    }
    __syncthreads();
    F2U c; c.f = make_float2(v * invn_s, 0.f);
    slots[t] = c.u;
    #pragma unroll
    for (int p = 1; p < PSLOT; p++) slots[(size_t)p * DIM + t] = CANARY;
    if (t < NBLOCKS) arrive[t] = 0u;     // monotone epoch flags, one u32 per block
}

// ---------------------------------------------------------------- Bessel coefs
// c_n(k) = (n==0?1:2) * (-i)^n * J_n(tau_k),  tau_k = theta_k * BBOUND
__global__ __launch_bounds__(256) void bessel_coef(const float* __restrict__ theta,
                                                   float2* __restrict__ coefs) {
    int n = blockIdx.x;   // 0..NMAX-1
    int k = blockIdx.y;   // 0..K_GATES-1
    double tau = (double)theta[k] * (double)BBOUND;
    int t = threadIdx.x;  // 256
    double acc = 0.0;
    #pragma unroll
    for (int i = 0; i < QUAD_M / 256; i++) {
        int j = t + 256 * i;
        double phi = (2.0 * M_PI / (double)QUAD_M) * (double)j;
        acc += cos((double)n * phi - tau * sin(phi));
    }
    #pragma unroll
    for (int o = 1; o < 64; o <<= 1) acc += __shfl_xor(acc, o);
    __shared__ double red[4];
    if ((t & 63) == 0) red[t >> 6] = acc;
    __syncthreads();
    if (t == 0) {
        double J = (red[0] + red[1] + red[2] + red[3]) / (double)QUAD_M;
        double f = (n == 0) ? 1.0 : 2.0;
        float cr = 0.f, cim = 0.f;
        switch (n & 3) {                 // (-i)^n
            case 0: cr  =  (float)(f * J); break;
            case 1: cim = -(float)(f * J); break;
            case 2: cr  = -(float)(f * J); break;
            case 3: cim =  (float)(f * J); break;
        }
        coefs[k * NMAX + n] = make_float2(cr, cim);
    }
}

// ---------------------------------------------------------------- truncation
__global__ __launch_bounds__(NMAX) void trunc_len(const float2* __restrict__ coefs,
                                                  int* __restrict__ nterm) {
    int k = blockIdx.x;
    int t = threadIdx.x;  // 512
    float2 c = coefs[k * NMAX + t];
    float mag = fabsf(c.x) + fabsf(c.y);
    int myn = (mag > 5e-7f) ? t : 0;
    #pragma unroll
    for (int o = 1; o < 64; o <<= 1) myn = max(myn, __shfl_xor(myn, o));
    __shared__ int red[8];
    if ((t & 63) == 0) red[t >> 6] = myn;
    __syncthreads();
    if (t == 0) {
        int m = 1;
        for (int i = 0; i < 8; i++) if (red[i] > m) m = red[i];
        nterm[k] = min(m, NMAX - 1);
    }
}

// ---------------------------------------------------------------- main kernel
//
// R5 structure with the R5-NaN repair. Memory-model lesson (R5 post-mortem):
// vmcnt-drain does NOT guarantee MALL visibility ORDER between two stores, so
// "flag visible => earlier data visible" is unsound. Design rule applied here:
//  * The DATA path trusts only the data's own sentinel: after release, any
//    still-CANARY component is re-polled (throttled, s_sleep(1)) until its
//    value arrives. Ordering-oblivious; CANARY is self-validating; no ABA
//    (each ring slot holds exactly CANARY -> one value per epoch).
//  * The FLAG path (arrive[b] = rho, plain relaxed store) is used ONLY for
//    inferences that depend on the flag's VALUE, never on store order:
//    arrive[b] >= rho can never be observed EARLY (the value does not exist
//    before block b's t0 passes that program point), so release(rho) =>
//    every block published rho => every block finished consuming slot rho-1
//    => re-arm of slot rho-1 is safe. Delayed flag visibility only delays
//    release (liveness fine, flags monotone).
//  * Round rho: dot from xs -> publish into slot[rho%8] -> sync (drain) ->
//    arrive[b]=rho -> ONE speculative component load (latency hides under
//    the poll) -> wave0 polls 64 flags in one coalesced 256B load ->
//    sync (release) -> throttled straggler re-poll of CANARY components ->
//    stage xs -> re-arm slot[rho-1] -> sync. Traffic bounded: 1 spec load +
//    rare post-release retries per thread per round (no R1/R4 flood).
//  * Last gate-round publishes acc directly (epilogue folded, R4-proven).
//  * Geometry: 64x1024, 16 rows/block, 1 row/wave; Gtilde row in VGPRs
//    (gq[8] float4, R4-proven); dot reads only xs from LDS.
__global__ __launch_bounds__(NTHREADS) void evolve(
        const float* __restrict__ gre, const float* __restrict__ gim,
        unsigned long long* __restrict__ slots,
        const float2* __restrict__ coefs, const int* __restrict__ nterm,
        unsigned int* __restrict__ arrive, float* __restrict__ out) {
    __shared__ float2 Gs[ROWS * DIM];        // 128 KiB: staging scratch for Gtilde
    __shared__ float2 xs[2][DIM];            // 16 KiB double-buffered vector
    const int t = threadIdx.x, b = blockIdx.x;
    const int wave = t >> 6, lane = t & 63;
    const int r0 = b * ROWS;
    const int r = r0 + wave;                 // this wave's row
    const float hB = 0.5f / BBOUND;

    // pre-stage psi (slot0, written by init_state — cross-kernel visible)
    { F2U c; c.u = ld64coh(slots + t); xs[0][t] = c.f; }
    float2 acc = make_float2(0.f, 0.f);
    float2 t1 = acc, t2 = acc;
    int rho = 1;
    __syncthreads();

    for (int k = 0; k < K_GATES; ++k) {
        const float* R = gre + (size_t)k * DIM * DIM;
        const float* I = gim + (size_t)k * DIM * DIM;

        // ---- stage Gtilde = ((R+R^T)/2 + i(I-I^T)/2)/B into Gs (R0 code) ----
        __syncthreads();                     // prior gate's gq pulls complete
        {   // pass A: column panel R[:, r0:r0+16], I[:, r0:r0+16]
            const float4* Rc = (const float4*)(R + (size_t)t * DIM + r0);
            const float4* Ic = (const float4*)(I + (size_t)t * DIM + r0);
            float4 ra0 = Rc[0], ra1 = Rc[1], ra2 = Rc[2], ra3 = Rc[3];
            float4 ia0 = Ic[0], ia1 = Ic[1], ia2 = Ic[2], ia3 = Ic[3];
            Gs[ 0 * DIM + t] = make_float2(hB * ra0.x, -hB * ia0.x);
            Gs[ 1 * DIM + t] = make_float2(hB * ra0.y, -hB * ia0.y);
            Gs[ 2 * DIM + t] = make_float2(hB * ra0.z, -hB * ia0.z);
            Gs[ 3 * DIM + t] = make_float2(hB * ra0.w, -hB * ia0.w);
            Gs[ 4 * DIM + t] = make_float2(hB * ra1.x, -hB * ia1.x);
            Gs[ 5 * DIM + t] = make_float2(hB * ra1.y, -hB * ia1.y);
            Gs[ 6 * DIM + t] = make_float2(hB * ra1.z, -hB * ia1.z);
            Gs[ 7 * DIM + t] = make_float2(hB * ra1.w, -hB * ia1.w);
            Gs[ 8 * DIM + t] = make_float2(hB * ra2.x, -hB * ia2.x);
            Gs[ 9 * DIM + t] = make_float2(hB * ra2.y, -hB * ia2.y);
            Gs[10 * DIM + t] = make_float2(hB * ra2.z, -hB * ia2.z);
            Gs[11 * DIM + t] = make_float2(hB * ra2.w, -hB * ia2.w);
            Gs[12 * DIM + t] = make_float2(hB * ra3.x, -hB * ia3.x);
            Gs[13 * DIM + t] = make_float2(hB * ra3.y, -hB * ia3.y);
            Gs[14 * DIM + t] = make_float2(hB * ra3.z, -hB * ia3.z);
            Gs[15 * DIM + t] = make_float2(hB * ra3.w, -hB * ia3.w);
        }
        __syncthreads();
        {   // pass B: row panel (coalesced), accumulate into Gs
            const float4* Rr = (const float4*)(R + (size_t)r * DIM);
            const float4* Ir = (const float4*)(I + (size_t)r * DIM);
            float4* G4 = (float4*)(Gs + (size_t)wave * DIM);
            #pragma unroll
            for (int m = 0; m < 4; m++) {
                int i4 = lane + 64 * m;
                float4 rv = Rr[i4], iv = Ir[i4];
                float4 g0 = G4[2 * i4], g1 = G4[2 * i4 + 1];
                g0.x += hB * rv.x; g0.y += hB * iv.x;
                g0.z += hB * rv.y; g0.w += hB * iv.y;
                g1.x += hB * rv.z; g1.y += hB * iv.z;
                g1.z += hB * rv.w; g1.w += hB * iv.w;
                G4[2 * i4] = g0; G4[2 * i4 + 1] = g1;
            }
        }
        __syncthreads();
        // pull this wave's row into registers: gq[m] covers comps 2(lane+64m)..+1
        float4 gq[8];
        #pragma unroll
        for (int m = 0; m < 8; ++m)
            gq[m] = *(const float4*)(Gs + (size_t)wave * DIM + 2 * (lane + 64 * m));

        const int N = nterm[k];
        const float2* C = coefs + (size_t)k * NMAX;

        for (int n = 1; n <= N; ++n, ++rho) {
            unsigned long long* dst = slots + (size_t)(rho & (PSLOT - 1)) * DIM;
            const float2* xsrc = xs[(rho - 1) & 1];

            // ---- w = Gtilde_row . x (regs x LDS), all-lane butterfly ----
            float sre = 0.f, sim = 0.f;
            const float4* x4 = (const float4*)xsrc;
            #pragma unroll
            for (int m = 0; m < 8; ++m) {
                float4 xv = x4[lane + 64 * m];
                float4 gv = gq[m];
                sre += gv.x * xv.x - gv.y * xv.y + gv.z * xv.z - gv.w * xv.w;
                sim += gv.x * xv.y + gv.y * xv.x + gv.z * xv.w + gv.w * xv.z;
            }
            #pragma unroll
            for (int o = 1; o < 64; o <<= 1) {
                sre += __shfl_xor(sre, o);
                sim += __shfl_xor(sim, o);
            }

            float2 tn;
            if (n == 1) {                    // T_0 = psi (staged), T_1 = Gt psi
                tn = make_float2(sre, sim);
                const float2 p0 = xsrc[r];
                const float2 c0 = C[0], c1 = C[1];
                acc.x = c0.x * p0.x - c0.y * p0.y + c1.x * tn.x - c1.y * tn.y;
                acc.y = c0.x * p0.y + c0.y * p0.x + c1.x * tn.y + c1.y * tn.x;
                t2 = p0;
            } else {                         // T_n = 2 Gt T_{n-1} - T_{n-2}
                tn = make_float2(2.f * sre - t2.x, 2.f * sim - t2.y);
                const float2 cn = C[n];
                acc.x += cn.x * tn.x - cn.y * tn.y;
                acc.y += cn.x * tn.y + cn.y * tn.x;
                t2 = t1;
            }
            t1 = tn;
            // last gate-round publishes the NEW psi (T_N is never consumed)
            const float2 res = (n == N) ? acc : tn;

            if (lane == 0) { F2U c; c.f = res; st64coh(dst + r, c.u); }
            __syncthreads();                 // drains every thread's stores

            // arrival flag: ONE plain store, monotone epoch (no RMW chain).
            // Its VALUE can never be observed early; order vs data NOT assumed.
            if (t == 0)
                __hip_atomic_store(&arrive[b], (unsigned)rho,
                                   __ATOMIC_RELAXED, __HIP_MEMORY_SCOPE_AGENT);

            // speculative component load — single issue, flies during the poll
            unsigned long long u = ld64coh(dst + t);

            // detect: wave 0, one coalesced 256B flag load per iteration
            if (wave == 0) {
                for (;;) {
                    unsigned v = __hip_atomic_load(&arrive[lane], __ATOMIC_RELAXED,
                                                   __HIP_MEMORY_SCOPE_AGENT);
                    if (__all((int)(v >= (unsigned)rho))) break;
                    __builtin_amdgcn_s_sleep(1);
                }
            }
            __syncthreads();                 // release: all 64 blocks published

            // straggler re-poll, throttled: tolerates publish-visibility lag
            // (R5 lesson — flag visibility does NOT order data visibility).
            // Post-release misses are rare & short-lived: 1-3 iterations.
            while (u == CANARY) {
                __builtin_amdgcn_s_sleep(1);
                u = ld64coh(dst + t);
            }
            { F2U c; c.u = u; xs[rho & 1][t] = c.f; }

            // re-arm slot[rho-1] (dead: all blocks consumed it before publishing
            // round rho — inference uses only the flag VALUE, so it is sound)
            if (t < ROWS)
                st64coh(slots + (size_t)((rho - 1) & (PSLOT - 1)) * DIM + r0 + t,
                        CANARY);
            __syncthreads();                 // xs complete for next round's dot
        }
    }

    // probs = |psi|^2 (acc holds this wave's row of the final state)
    if (lane == 0) out[r] = acc.x * acc.x + acc.y * acc.y;
}

// ---------------------------------------------------------------- launch
extern "C" void kernel_launch(void* const* d_in, const int* in_sizes, int n_in,
                              void* d_out, int out_size, void* d_ws, size_t ws_size,
                              hipStream_t stream) {
    const float* feat  = (const float*)d_in[0];   // 1000
    const float* theta = (const float*)d_in[1];   // 24
    const float* gre   = (const float*)d_in[2];   // 24*1024*1024
    const float* gim   = (const float*)d_in[3];

    // ws: slots[8][1024] u64 | coefs[24][512] f2 | nterm[24] i32 | pad | arrive[64] u32
    char* base = (char*)d_ws;
    unsigned long long* slots = (unsigned long long*)base;
    size_t off = (size_t)PSLOT * DIM * sizeof(unsigned long long);
    float2* coefs = (float2*)(base + off);
    off += (size_t)K_GATES * NMAX * sizeof(float2);
    int* nterm = (int*)(base + off);
    off += (size_t)K_GATES * sizeof(int);
    off = (off + 255) & ~(size_t)255;
    unsigned int* arrive = (unsigned int*)(base + off);
    float* outp = (float*)d_out;

    init_state<<<1, 1024, 0, stream>>>(feat, in_sizes[0], slots, arrive);
    bessel_coef<<<dim3(NMAX, K_GATES), 256, 0, stream>>>(theta, coefs);
    trunc_len<<<K_GATES, NMAX, 0, stream>>>(coefs, nterm);

    void* args[] = {(void*)&gre, (void*)&gim, (void*)&slots,
                    (void*)&coefs, (void*)&nterm, (void*)&arrive, (void*)&outp};
    hipLaunchCooperativeKernel((void*)evolve, dim3(NBLOCKS), dim3(NTHREADS),
                               args, 0, stream);
}